// Round 1
// baseline (230.165 us; speedup 1.0000x reference)
//
#include <hip/hip_runtime.h>
#include <stdint.h>
#include <stddef.h>

// Problem constants (B, F, D) = (1024, 16, 64); P = 120
constexpr int NB = 1024;
constexpr int NF = 16;
constexpr int ND = 64;
constexpr int NP = 120;
constexpr int KD = ND * ND;          // 4096 (contraction length per pair)
constexpr int OUT_STRIDE = NP * ND;  // 7680 floats per batch row

using floatx4 = __attribute__((ext_vector_type(4))) float;
using short8  = __attribute__((ext_vector_type(8))) short;
using uint4v  = __attribute__((ext_vector_type(4))) uint32_t;

// LDS row strides chosen for 16B alignment + bank-conflict-free reads
constexpr int XI_STRIDE = 68;  // fp32 elems: 272 B rows (16B-aligned, 2-way banks = free)
constexpr int BT_STRIDE = 72;  // bf16 elems: 144 B rows (16B-aligned, 2-way banks = free)

// round-half-up f32->bf16, two at a time, packed into one dword (3 VALU ops)
__device__ __forceinline__ uint32_t pack_bf16(float f0, float f1) {
    uint32_t u0 = __float_as_uint(f0) + 0x8000u;
    uint32_t u1 = __float_as_uint(f1) + 0x8000u;
    // take hi16 of each: byte sel 0x07060302 -> (hi16(u1)<<16) | hi16(u0)
    return __builtin_amdgcn_perm(u1, u0, 0x07060302u);
}

__global__ __launch_bounds__(256, 2)
void outer_kernel(const float* __restrict__ x, const float* __restrict__ W,
                  const float* __restrict__ bias, float* __restrict__ out)
{
    __shared__ float    lds_xi[256 * XI_STRIDE];  // 69,632 B
    __shared__ uint16_t lds_bt[ND * BT_STRIDE];   //  9,216 B  (total 78,848 -> 2 blocks/CU)

    const int p  = blockIdx.x;        // pair index 0..119
    const int b0 = blockIdx.y * 256;  // batch tile origin

    // triu_indices(16, k=1) order: (0,1),(0,2),...,(0,15),(1,2),...
    int icol = 0, rem = p;
    while (rem >= NF - 1 - icol) { rem -= NF - 1 - icol; ++icol; }
    const int jcol = icol + 1 + rem;

    const int t    = threadIdx.x;
    const int wave = t >> 6;      // 0..3, owns batch rows [wave*64, wave*64+64)
    const int lane = t & 63;
    const int r    = lane & 15;
    const int quad = lane >> 4;

    // ---- stage xi tile: x[b0+m][icol][0..63] -> lds_xi[m][a] (fp32 copy) ----
    {
        const float* src = x + (size_t)(b0 + t) * (NF * ND) + icol * ND;
        float* dst = lds_xi + t * XI_STRIDE;
        #pragma unroll
        for (int c = 0; c < ND; c += 4)
            *(floatx4*)(dst + c) = *(const floatx4*)(src + c);
    }

    // ---- preload xj windows into registers (fp32, live across whole K-loop) ----
    // A-frag (16x16x32): lane holds A[m = lane&15][k = quad*8 + j], j=0..7
    // A[m][k_local=c] for a-step a:  xi[m,a] * xj[m,c],  c = ks*32 + quad*8 + j
    float xj[4][2][8];
    #pragma unroll
    for (int ms = 0; ms < 4; ++ms) {
        const float* srow = x + (size_t)(b0 + wave*64 + ms*16 + r) * (NF * ND)
                              + jcol * ND + quad * 8;
        #pragma unroll
        for (int ks = 0; ks < 2; ++ks) {
            floatx4 v0 = *(const floatx4*)(srow + ks * 32);
            floatx4 v1 = *(const floatx4*)(srow + ks * 32 + 4);
            xj[ms][ks][0] = v0.x; xj[ms][ks][1] = v0.y;
            xj[ms][ks][2] = v0.z; xj[ms][ks][3] = v0.w;
            xj[ms][ks][4] = v1.x; xj[ms][ks][5] = v1.y;
            xj[ms][ks][6] = v1.z; xj[ms][ks][7] = v1.w;
        }
    }

    // ---- W staging assignment: thread covers (n_st, c_st..c_st+15) of the 64x64 a-tile
    const int n_st = t >> 2;           // 0..63 (output channel row)
    const int c_st = (t & 3) * 16;     // 0,16,32,48
    const float* wsrc = W + ((size_t)p * ND + n_st) * KD + c_st;
    uint16_t* bdst = lds_bt + n_st * BT_STRIDE + c_st;

    // prefetch a = 0
    floatx4 w0 = *(const floatx4*)(wsrc + 0);
    floatx4 w1 = *(const floatx4*)(wsrc + 4);
    floatx4 w2 = *(const floatx4*)(wsrc + 8);
    floatx4 w3 = *(const floatx4*)(wsrc + 12);

    floatx4 acc[4][4] = {};  // 4 msub x 4 nsub C-frags (64 VGPRs)

    #pragma unroll 1
    for (int a = 0; a < ND; ++a) {
        // write prefetched W tile to LDS as bf16 (Bt[n][c] = W[p][n][a*64+c])
        uint4v q0 = (uint4v){ pack_bf16(w0.x, w0.y), pack_bf16(w0.z, w0.w),
                              pack_bf16(w1.x, w1.y), pack_bf16(w1.z, w1.w) };
        uint4v q1 = (uint4v){ pack_bf16(w2.x, w2.y), pack_bf16(w2.z, w2.w),
                              pack_bf16(w3.x, w3.y), pack_bf16(w3.z, w3.w) };
        *(uint4v*)(bdst)     = q0;
        *(uint4v*)(bdst + 8) = q1;
        __syncthreads();

        // prefetch next a-step (hidden behind the 32 MFMAs below)
        if (a + 1 < ND) {
            const float* wn = wsrc + (size_t)(a + 1) * ND;
            w0 = *(const floatx4*)(wn + 0);
            w1 = *(const floatx4*)(wn + 4);
            w2 = *(const floatx4*)(wn + 8);
            w3 = *(const floatx4*)(wn + 12);
        }

        // xi scalars for this a-step (one per msub)
        float xis[4];
        #pragma unroll
        for (int ms = 0; ms < 4; ++ms)
            xis[ms] = lds_xi[(wave*64 + ms*16 + r) * XI_STRIDE + a];

        #pragma unroll
        for (int ks = 0; ks < 2; ++ks) {
            // B-frag (16x16x32): lane holds B[k = quad*8+j][n = lane&15]
            short8 bf[4];
            #pragma unroll
            for (int ns = 0; ns < 4; ++ns)
                bf[ns] = *(const short8*)&lds_bt[(ns*16 + r) * BT_STRIDE
                                                 + ks*32 + quad*8];
            #pragma unroll
            for (int ms = 0; ms < 4; ++ms) {
                union { short8 s; uint32_t u[4]; } af;
                #pragma unroll
                for (int jj = 0; jj < 4; ++jj)
                    af.u[jj] = pack_bf16(xis[ms] * xj[ms][ks][2*jj],
                                         xis[ms] * xj[ms][ks][2*jj + 1]);
                #pragma unroll
                for (int ns = 0; ns < 4; ++ns)
                    acc[ms][ns] = __builtin_amdgcn_mfma_f32_16x16x32_bf16(
                        af.s, bf[ns], acc[ms][ns], 0, 0, 0);
            }
        }
        __syncthreads();
    }

    // ---- epilogue: bias + store. C/D layout: col = lane&15, row = quad*4 + reg ----
    #pragma unroll
    for (int ns = 0; ns < 4; ++ns) {
        const float bb = bias[p * ND + ns*16 + r];
        #pragma unroll
        for (int ms = 0; ms < 4; ++ms) {
            #pragma unroll
            for (int reg = 0; reg < 4; ++reg) {
                const int row = b0 + wave*64 + ms*16 + quad*4 + reg;
                out[(size_t)row * OUT_STRIDE + p * ND + ns*16 + r]
                    = acc[ms][ns][reg] + bb;
            }
        }
    }
}

extern "C" void kernel_launch(void* const* d_in, const int* in_sizes, int n_in,
                              void* d_out, int out_size, void* d_ws, size_t ws_size,
                              hipStream_t stream) {
    const float* x    = (const float*)d_in[0];  // (1024, 16, 64)
    const float* W    = (const float*)d_in[1];  // (120, 64, 4096)
    const float* bias = (const float*)d_in[2];  // (120, 64)
    float* out = (float*)d_out;                 // (1024, 120, 64)

    dim3 grid(NP, NB / 256);   // 120 pairs x 4 batch tiles = 480 blocks
    outer_kernel<<<grid, 256, 0, stream>>>(x, W, bias, out);
}